// Round 15
// baseline (152.549 us; speedup 1.0000x reference)
//
#include <hip/hip_runtime.h>
#include <hip/hip_bf16.h>

// transformAttention fused MFMA kernel (round 15)
// r13/r14 post-mortem: bit-identical wrong absmax across two compiles =
// deterministic logic bug in the wave-private-project chassis; abandoned.
// Round 15 rebuilds the occupancy gain from r10-VERIFIED pieces only:
//   LDS 24576 (q-slab + k-slab, no v-slab) -> 6 blocks/CU (was 4).
//   Phase 1: q,k projection (r10 job machinery, 12 jobs). B1.
//   2a: r10 verbatim + s-clamp on garbage lanes (OOB-safety with shrunk LDS).
//   B2 (q,k dead block-wide) -> v projected into dead q-slab (6 jobs). B3.
//   vv -> regs; pbuf in dead k-slab (per-wave 3072B), ni SEQUENTIAL:
//   scatter->fence->PV->fence; tbuf overlays pbuf (r10 fence pattern);
//   FFN + stores r10-verbatim.
// 3 __syncthreads, wave-local fences elsewhere.

typedef __attribute__((ext_vector_type(8))) short bf16x8;
typedef __attribute__((ext_vector_type(4))) float f32x4;

constexpr int Bb = 16, Ss = 12, Nn = 2048, Dd = 64;
constexpr float EXPK = 0.51011687f;   // (1/sqrt(8)) * log2(e)
constexpr int KOFS = 12288, LDSZ = 24576;

#define MFMA16(A, B, C) __builtin_amdgcn_mfma_f32_16x16x32_bf16((A), (B), (C), 0, 0, 0)

__device__ __forceinline__ short f2bf(float f) {
    __hip_bfloat16 h = __float2bfloat16(f);
    short s; __builtin_memcpy(&s, &h, 2); return s;
}
__device__ __forceinline__ float bitf(unsigned u) {
    float f; __builtin_memcpy(&f, &u, 4); return f;
}
__device__ __forceinline__ float bf2f(unsigned short v) {
    return bitf(((unsigned)v) << 16);
}
__device__ __forceinline__ unsigned cvtpk(float lo, float hi) {
    unsigned r;
    asm("v_cvt_pk_bf16_f32 %0, %1, %2" : "=v"(r) : "v"(lo), "v"(hi));
    return r;
}
__device__ __forceinline__ void lds_fence() {
    asm volatile("s_waitcnt lgkmcnt(0)" ::: "memory");
    __builtin_amdgcn_sched_barrier(0);
}
// q/k slab byte offset (r10's verified swizzle), t in {0,1}
__device__ __forceinline__ int qkOfs(int t, int s, int n, int d) {
    return t * KOFS + s * 1024 + n * 128 + ((2 * d) ^ (((s & 7) ^ (n & 7)) << 4));
}
// tbuf rows (r10's tOfs formula)
__device__ __forceinline__ int tRow(int row, int d) {
    return row * 128 + ((2 * d) ^ ((row & 7) << 4));
}

// prep: d_ws <- bf16 W^T for Wff, W1, W2: wt[m][r*64+c] = W[c][r]
__global__ void prep_w(const float* __restrict__ Wff, const float* __restrict__ W1,
                       const float* __restrict__ W2, unsigned short* __restrict__ wt) {
    int idx = blockIdx.x * 256 + threadIdx.x;
    if (idx >= 3 * 4096) return;
    int m = idx >> 12, rc = idx & 4095, r = rc >> 6, c = rc & 63;
    const float* W = (m == 0) ? Wff : (m == 1) ? W1 : W2;
    unsigned short u; short s = f2bf(W[c * 64 + r]);
    __builtin_memcpy(&u, &s, 2);
    wt[idx] = u;
}

__global__ __launch_bounds__(256, 4)
void ta_mfma13(const float* __restrict__ x,
               const float* __restrict__ steP,
               const float* __restrict__ steQ,
               const float* __restrict__ bff, const float* __restrict__ b1,
               const float* __restrict__ b2,
               const unsigned short* __restrict__ wt,
               float* __restrict__ out)
{
    alignas(16) __shared__ char smem[LDSZ];

    const int tid = threadIdx.x;
    const int w   = tid >> 6;      // 0..3
    const int l   = tid & 63;
    const int l15 = l & 15;
    const int l4  = l >> 4;
    const int b   = blockIdx.y;
    const int n0  = blockIdx.x * 8;

    // ---- W_ff B-frags (bf16, pre-transposed in d_ws) ----
    bf16x8 wf[4][2];
    float bfv[4];
    #pragma unroll
    for (int nt = 0; nt < 4; ++nt) {
        bfv[nt] = bff[nt * 16 + l15];
        #pragma unroll
        for (int kc = 0; kc < 2; ++kc)
            wf[nt][kc] = *(const bf16x8*)(wt + (nt * 16 + l15) * 64 + kc * 32 + l4 * 8);
    }

    // ---- r10's projection job (M-tile = 2s x 8n), writes slab slot t ----
    const int sA = l15 >> 3, nA = l15 & 7;
    auto do_job = [&](const float* base, int tSlot, int s0) {
        const float* rp = base + ((size_t)(b * Ss + s0 + sA) * Nn + n0 + nA) * Dd + l4 * 8;
        bf16x8 a[2];
        #pragma unroll
        for (int kc = 0; kc < 2; ++kc) {
            float4 p0 = *(const float4*)(rp + kc * 32);
            float4 p1 = *(const float4*)(rp + kc * 32 + 4);
            union { unsigned u[4]; bf16x8 v; } cv;
            cv.u[0] = cvtpk(p0.x, p0.y); cv.u[1] = cvtpk(p0.z, p0.w);
            cv.u[2] = cvtpk(p1.x, p1.y); cv.u[3] = cvtpk(p1.z, p1.w);
            a[kc] = cv.v;
        }
        #pragma unroll
        for (int nt = 0; nt < 4; ++nt) {
            f32x4 acc = { bfv[nt], bfv[nt], bfv[nt], bfv[nt] };
            acc = MFMA16(a[0], wf[nt][0], acc);
            acc = MFMA16(a[1], wf[nt][1], acc);
            const int d = nt * 16 + l15;
            #pragma unroll
            for (int q = 0; q < 4; ++q) {
                const int r = l4 * 4 + q, s = s0 + (r >> 3), nn = r & 7;
                *(short*)(smem + qkOfs(tSlot, s, nn, d)) = f2bf(acc[q]);
            }
        }
    };

    // ---- phase 1: q,k projections, 12 jobs over 4 waves ----
    for (int job = w; job < 12; job += 4) {
        const int t = job / 6, s0 = (job % 6) * 2;
        do_job((t == 0) ? steQ : steP, t, s0);
    }
    __syncthreads();   // B1: q,k ready

    // ---- phase 2a: per-head QK^T (swapped) + softmax; both ni interleaved ----
    const int sE = (l15 < 12) ? l15 : 11;   // clamp garbage lanes (OOB safety)
    unsigned pw[2][8][2];
    #pragma unroll
    for (int h = 0; h < 8; ++h) {
        #pragma unroll
        for (int ni = 0; ni < 2; ++ni) {
            const int n = w * 2 + ni;
            union { unsigned u[4]; bf16x8 v; } akk;
            akk.v = *(const bf16x8*)(smem + qkOfs(1, sE, n, h * 8));
            bf16x8 aq = *(const bf16x8*)(smem + qkOfs(0, sE, n, h * 8));
            if (l4 != 0) { akk.u[0] = 0; akk.u[1] = 0; akk.u[2] = 0; akk.u[3] = 0; }
            f32x4 c = { 0.f, 0.f, 0.f, 0.f };
            c = MFMA16(akk.v, aq, c);     // S^T: row p = l4*4+reg, col q = l15
            float e[4];
            #pragma unroll
            for (int i = 0; i < 4; ++i) {
                float v = __builtin_amdgcn_exp2f(c[i] * EXPK);
                e[i] = (l4 == 3) ? 0.f : v;     // zero p >= 12 / garbage rows
            }
            float ssum = (e[0] + e[1]) + (e[2] + e[3]);
            ssum += __shfl_xor(ssum, 16);
            ssum += __shfl_xor(ssum, 32);
            float inv;
            asm("v_rcp_f32 %0, %1" : "=v"(inv) : "v"(ssum));
            pw[ni][h][0] = cvtpk(e[0] * inv, e[1] * inv);
            pw[ni][h][1] = cvtpk(e[2] * inv, e[3] * inv);
        }
    }
    __syncthreads();   // B2: q,k slabs dead block-wide

    // ---- phase 1v: v projections into dead q-slab, 6 jobs over 4 waves ----
    for (int job = w; job < 6; job += 4)
        do_job(x, 0, job * 2);
    __syncthreads();   // B3: v visible block-wide

    // ---- v rows into regs (lane = d), both ni ----
    float vv[2][12];
    #pragma unroll
    for (int ni = 0; ni < 2; ++ni)
        #pragma unroll
        for (int s = 0; s < 12; ++s)
            vv[ni][s] = bf2f(*(const unsigned short*)(smem + qkOfs(0, s, w * 2 + ni, l)));
    lds_fence();   // vv reads retired (q-slab untouched hereafter; k-slab next)

    // ---- phase 2b: pbuf in dead k-slab (per-wave 3072B), ni sequential ----
    char* const pbBase = smem + KOFS + w * 3072;
    const int hslot = (l >> 3) * 32;   // lane's head = d>>3
    float oacc[2][12];
    #pragma unroll
    for (int ni = 0; ni < 2; ++ni) {
        if (l15 < 12 && l4 < 3) {
            #pragma unroll
            for (int h = 0; h < 8; ++h) {
                uint2 u; u.x = pw[ni][h][0]; u.y = pw[ni][h][1];
                *(uint2*)(pbBase + l15 * 256 + ((h * 32) ^ ((l15 & 7) << 5)) + l4 * 8) = u;
            }
        }
        lds_fence();   // RAW: pbuf visible (wave-local)
        #pragma unroll
        for (int q = 0; q < 12; ++q) {
            const char* qp = pbBase + q * 256 + (hslot ^ ((q & 7) << 5));
            uint4 pa = *(const uint4*)(qp);
            uint2 pbx = *(const uint2*)(qp + 16);
            const unsigned wds[6] = { pa.x, pa.y, pa.z, pa.w, pbx.x, pbx.y };
            float a = 0.f;
            #pragma unroll
            for (int p2 = 0; p2 < 6; ++p2) {
                a = fmaf(bitf(wds[p2] << 16),         vv[ni][2 * p2],     a);
                a = fmaf(bitf(wds[p2] & 0xFFFF0000u), vv[ni][2 * p2 + 1], a);
            }
            oacc[ni][q] = a;
        }
        lds_fence();   // WAR: pbuf reads retired before overwrite (next ni / tbuf)
    }

    // ---- tbuf (overlays pbuf region, per-ni 1536B; r10 fence pattern) ----
    #pragma unroll
    for (int ni = 0; ni < 2; ++ni)
        #pragma unroll
        for (int q = 0; q < 12; ++q)
            *(short*)(pbBase + ni * 1536 + tRow(q, l)) = f2bf(oacc[ni][q]);
    lds_fence();   // RAW: tbuf visible

    const int l15c = (l15 < 12) ? l15 : 0;   // clamp B rows 12..15 (cols discarded)

    // ---- phase 3: FFN, wave-private, both ni ----
    {
        bf16x8 w1f[4][2];
        float b1v[4];
        #pragma unroll
        for (int nt = 0; nt < 4; ++nt) {
            b1v[nt] = b1[nt * 16 + l15];
            #pragma unroll
            for (int kc = 0; kc < 2; ++kc)
                w1f[nt][kc] = *(const bf16x8*)(wt + 4096 + (nt * 16 + l15) * 64 + kc * 32 + l4 * 8);
        }
        #pragma unroll
        for (int ni = 0; ni < 2; ++ni) {
            bf16x8 a[2];
            #pragma unroll
            for (int kc = 0; kc < 2; ++kc)
                a[kc] = *(const bf16x8*)(pbBase + ni * 1536 + tRow(l15c, kc * 32 + l4 * 8));
            #pragma unroll
            for (int nt = 0; nt < 4; ++nt) {
                f32x4 acc = { b1v[nt], b1v[nt], b1v[nt], b1v[nt] };
                acc = MFMA16(a[0], w1f[nt][0], acc);
                acc = MFMA16(a[1], w1f[nt][1], acc);
                #pragma unroll
                for (int reg = 0; reg < 4; ++reg) {
                    const int rt = l4 * 4 + reg;
                    if (rt < 12)
                        *(short*)(pbBase + ni * 1536 + tRow(rt, nt * 16 + l15)) =
                            f2bf(fmaxf(acc[reg], 0.f));   // in-place (r10-verified)
                }
            }
        }
    }
    lds_fence();   // RAW: hid visible
    {
        bf16x8 w2f[4][2];
        float b2v[4];
        #pragma unroll
        for (int nt = 0; nt < 4; ++nt) {
            b2v[nt] = b2[nt * 16 + l15];
            #pragma unroll
            for (int kc = 0; kc < 2; ++kc)
                w2f[nt][kc] = *(const bf16x8*)(wt + 8192 + (nt * 16 + l15) * 64 + kc * 32 + l4 * 8);
        }
        #pragma unroll
        for (int ni = 0; ni < 2; ++ni) {
            bf16x8 a[2];
            #pragma unroll
            for (int kc = 0; kc < 2; ++kc)
                a[kc] = *(const bf16x8*)(pbBase + ni * 1536 + tRow(l15c, kc * 32 + l4 * 8));
            #pragma unroll
            for (int nt = 0; nt < 4; ++nt) {
                f32x4 acc = { b2v[nt], b2v[nt], b2v[nt], b2v[nt] };
                acc = MFMA16(a[0], w2f[nt][0], acc);
                acc = MFMA16(a[1], w2f[nt][1], acc);
                #pragma unroll
                for (int reg = 0; reg < 4; ++reg) {
                    const int q = l4 * 4 + reg;
                    if (q < 12)
                        out[((size_t)(b * Ss + q) * Nn + n0 + w * 2 + ni) * Dd + nt * 16 + l15] = acc[reg];
                }
            }
        }
    }
}

extern "C" void kernel_launch(void* const* d_in, const int* in_sizes, int n_in,
                              void* d_out, int out_size, void* d_ws, size_t ws_size,
                              hipStream_t stream) {
    const float* x    = (const float*)d_in[0];
    const float* steP = (const float*)d_in[1];
    const float* steQ = (const float*)d_in[2];
    const float* Wff  = (const float*)d_in[3];
    const float* bff  = (const float*)d_in[4];
    const float* W1   = (const float*)d_in[5];
    const float* b1   = (const float*)d_in[6];
    const float* W2   = (const float*)d_in[7];
    const float* b2   = (const float*)d_in[8];
    float* out = (float*)d_out;
    unsigned short* wtp = (unsigned short*)d_ws;

    prep_w<<<48, 256, 0, stream>>>(Wff, W1, W2, wtp);
    dim3 grid(Nn / 8, Bb);
    ta_mfma13<<<grid, 256, 0, stream>>>(x, steP, steQ, bff, b1, b2, wtp, out);
}

// Round 16
// 127.945 us; speedup vs baseline: 1.1923x; 1.1923x over previous
//
#include <hip/hip_runtime.h>
#include <hip/hip_bf16.h>

// transformAttention fused MFMA kernel (round 16)
// r15 post-mortem: v-after-2a overlapped pw with projection -> spills (WRITE
// +89MB); occupancy lever dead (compiler pins VGPR<=64, 4 failed attempts).
// r10 (127.6us) = verified chassis. Its stall budget: ~76 VMEM ops/wave with
// ~1-2 wave-instr outstanding (VGPR-capped) -> ~2 TB/s Little's-law cap.
// Round 16 = r10 + ONE change: phase-1 inputs staged via global_load_lds
// (width 16, VGPR-free payload): per job, 4 instrs stage the 16x256B f32 tile
// into a per-wave 4096B LDS buffer (XOR pre-swizzled GLOBAL src, m173 pattern,
// so linear LDS landing = conflict-free b128 readback), vmcnt(0), then r10's
// cvtpk->MFMA->slab stores verbatim. LDS 53248 -> still 3 blocks/CU.
// LDS map: [0,12288) q slab | [12288,24576) k slab (pbuf overlay post-B2)
//          [24576,36864) v slab (tbuf overlay) | [36864,53248) stage 4x4096

typedef __attribute__((ext_vector_type(8))) short bf16x8;
typedef __attribute__((ext_vector_type(4))) float f32x4;

constexpr int Bb = 16, Ss = 12, Nn = 2048, Dd = 64;
constexpr float EXPK = 0.51011687f;   // (1/sqrt(8)) * log2(e)
constexpr int KOFS = 12288, VOFS = 24576, STG = 36864, LDSZ = 53248;

#define MFMA16(A, B, C) __builtin_amdgcn_mfma_f32_16x16x32_bf16((A), (B), (C), 0, 0, 0)

__device__ __forceinline__ short f2bf(float f) {
    __hip_bfloat16 h = __float2bfloat16(f);
    short s; __builtin_memcpy(&s, &h, 2); return s;
}
__device__ __forceinline__ float bitf(unsigned u) {
    float f; __builtin_memcpy(&f, &u, 4); return f;
}
__device__ __forceinline__ float bf2f(unsigned short v) {
    return bitf(((unsigned)v) << 16);
}
__device__ __forceinline__ unsigned cvtpk(float lo, float hi) {
    unsigned r;
    asm("v_cvt_pk_bf16_f32 %0, %1, %2" : "=v"(r) : "v"(lo), "v"(hi));
    return r;
}
__device__ __forceinline__ void lds_fence() {
    asm volatile("s_waitcnt lgkmcnt(0)" ::: "memory");
    __builtin_amdgcn_sched_barrier(0);
}
__device__ __forceinline__ void vm_fence0() {
    asm volatile("s_waitcnt vmcnt(0)" ::: "memory");
    __builtin_amdgcn_sched_barrier(0);
}
// q/k/v slab byte offset (r10's verified swizzle)
__device__ __forceinline__ int qkOfs(int t, int s, int n, int d) {
    return t * KOFS + s * 1024 + n * 128 + ((2 * d) ^ (((s & 7) ^ (n & 7)) << 4));
}
// tbuf in v-slab: slot = w*2+ni, 12 rows x 128 B (r10 verbatim)
__device__ __forceinline__ int vtOfs(int slot, int row, int d) {
    return VOFS + slot * 1536 + row * 128 + ((2 * d) ^ ((row & 7) << 4));
}

// prep: d_ws <- bf16 W^T for Wff, W1, W2: wt[m][r*64+c] = W[c][r]
__global__ void prep_w(const float* __restrict__ Wff, const float* __restrict__ W1,
                       const float* __restrict__ W2, unsigned short* __restrict__ wt) {
    int idx = blockIdx.x * 256 + threadIdx.x;
    if (idx >= 3 * 4096) return;
    int m = idx >> 12, rc = idx & 4095, r = rc >> 6, c = rc & 63;
    const float* W = (m == 0) ? Wff : (m == 1) ? W1 : W2;
    unsigned short u; short s = f2bf(W[c * 64 + r]);
    __builtin_memcpy(&u, &s, 2);
    wt[idx] = u;
}

__global__ __launch_bounds__(256, 3)
void ta_mfma14(const float* __restrict__ x,
               const float* __restrict__ steP,
               const float* __restrict__ steQ,
               const float* __restrict__ bff, const float* __restrict__ b1,
               const float* __restrict__ b2,
               const unsigned short* __restrict__ wt,
               float* __restrict__ out)
{
    alignas(16) __shared__ char smem[LDSZ];

    const int tid = threadIdx.x;
    const int w   = tid >> 6;      // 0..3
    const int l   = tid & 63;
    const int l15 = l & 15;
    const int l4  = l >> 4;
    const int b   = blockIdx.y;
    const int n0  = blockIdx.x * 8;

    // ---- W_ff B-frags (bf16, pre-transposed in d_ws) ----
    bf16x8 wf[4][2];
    float bfv[4];
    #pragma unroll
    for (int nt = 0; nt < 4; ++nt) {
        bfv[nt] = bff[nt * 16 + l15];
        #pragma unroll
        for (int kc = 0; kc < 2; ++kc)
            wf[nt][kc] = *(const bf16x8*)(wt + (nt * 16 + l15) * 64 + kc * 32 + l4 * 8);
    }

    // ---- phase 1: staged projections ----
    // Stage: job tile = 16 rows x 256 B f32. LDS layout [row][256], row-swizzled
    // (contract: LDS byte row*256+z holds source byte z^((row&7)<<5)). Dest is
    // wave-linear (base+lane*16); the swizzle is applied to the GLOBAL src.
    char* const sbuf = smem + STG + w * 4096;
    const int nj = (w < 2) ? 5 : 4;   // jobs w, w+4, w+8, w+12 (+ w+16)

    for (int jj = 0; jj < nj; ++jj) {
        const int job = w + jj * 4;
        const int t = job / 6, s0 = (job % 6) * 2;
        const float* base = (t == 0) ? steQ : (t == 1) ? steP : x;

        lds_fence();   // WAR: prior job's stage-buffer reads retired
        #pragma unroll
        for (int i = 0; i < 4; ++i) {
            const int r = i * 4 + l4;          // tile row this lane stages
            const char* src = (const char*)base
                + ((size_t)(b * Ss + s0 + (r >> 3)) * Nn + n0 + (r & 7)) * 256
                + ((l15 * 16) ^ ((r & 7) << 5));
            __builtin_amdgcn_global_load_lds(
                (const __attribute__((address_space(1))) unsigned*)(const void*)src,
                (__attribute__((address_space(3))) unsigned*)(void*)(sbuf + i * 1024),
                16, 0, 0);
        }
        vm_fence0();   // stage landed

        const int rsw = (l15 & 7) << 5;
        bf16x8 a[2];
        #pragma unroll
        for (int kc = 0; kc < 2; ++kc) {
            const int d0 = kc * 128 + l4 * 32;
            f32x4 p0 = *(const f32x4*)(sbuf + l15 * 256 + (d0 ^ rsw));
            f32x4 p1 = *(const f32x4*)(sbuf + l15 * 256 + ((d0 + 16) ^ rsw));
            union { unsigned u[4]; bf16x8 v; } cv;
            cv.u[0] = cvtpk(p0[0], p0[1]); cv.u[1] = cvtpk(p0[2], p0[3]);
            cv.u[2] = cvtpk(p1[0], p1[1]); cv.u[3] = cvtpk(p1[2], p1[3]);
            a[kc] = cv.v;
        }
        #pragma unroll
        for (int nt = 0; nt < 4; ++nt) {
            f32x4 acc = { bfv[nt], bfv[nt], bfv[nt], bfv[nt] };
            acc = MFMA16(a[0], wf[nt][0], acc);
            acc = MFMA16(a[1], wf[nt][1], acc);
            const int d = nt * 16 + l15;
            #pragma unroll
            for (int q = 0; q < 4; ++q) {
                const int r = l4 * 4 + q, s = s0 + (r >> 3), nn = r & 7;
                *(short*)(smem + qkOfs(t, s, nn, d)) = f2bf(acc[q]);
            }
        }
    }
    __syncthreads();   // B1: q,k,v ready

    // ---- v rows into regs (lane = d), both ni ----
    float vv[2][12];
    #pragma unroll
    for (int ni = 0; ni < 2; ++ni)
        #pragma unroll
        for (int s = 0; s < 12; ++s)
            vv[ni][s] = bf2f(*(const unsigned short*)(smem + qkOfs(2, s, w * 2 + ni, l)));

    // ---- phase 2a: per-head QK^T (swapped) + softmax; both ni interleaved ----
    unsigned pw[2][8][2];
    #pragma unroll
    for (int h = 0; h < 8; ++h) {
        #pragma unroll
        for (int ni = 0; ni < 2; ++ni) {
            const int n = w * 2 + ni;
            union { unsigned u[4]; bf16x8 v; } akk;
            akk.v = *(const bf16x8*)(smem + qkOfs(1, l15, n, h * 8));
            bf16x8 aq = *(const bf16x8*)(smem + qkOfs(0, l15, n, h * 8));
            if (l4 != 0) { akk.u[0] = 0; akk.u[1] = 0; akk.u[2] = 0; akk.u[3] = 0; }
            f32x4 c = { 0.f, 0.f, 0.f, 0.f };
            c = MFMA16(akk.v, aq, c);     // S^T: row p = l4*4+reg, col q = l15
            float e[4];
            #pragma unroll
            for (int i = 0; i < 4; ++i) {
                float v = __builtin_amdgcn_exp2f(c[i] * EXPK);
                e[i] = (l4 == 3) ? 0.f : v;     // zero p >= 12 / garbage rows
            }
            float ssum = (e[0] + e[1]) + (e[2] + e[3]);
            ssum += __shfl_xor(ssum, 16);
            ssum += __shfl_xor(ssum, 32);
            float inv;
            asm("v_rcp_f32 %0, %1" : "=v"(inv) : "v"(ssum));
            pw[ni][h][0] = cvtpk(e[0] * inv, e[1] * inv);
            pw[ni][h][1] = cvtpk(e[2] * inv, e[3] * inv);
        }
    }
    __syncthreads();   // B2: q,k slabs dead -> per-wave pbuf region

    // ---- phase 2b: pbuf scatter + VALU PV, both ni (r10 verbatim) ----
    #pragma unroll
    for (int ni = 0; ni < 2; ++ni) {
        const int pb = w * 6144 + ni * 3072;
        if (l15 < 12 && l4 < 3) {
            #pragma unroll
            for (int h = 0; h < 8; ++h) {
                uint2 u; u.x = pw[ni][h][0]; u.y = pw[ni][h][1];
                *(uint2*)(smem + pb + l15 * 256 + ((h * 32) ^ ((l15 & 7) << 5)) + l4 * 8) = u;
            }
        }
    }
    lds_fence();

    float oacc[2][12];
    const int hslot = (l >> 3) * 32;   // lane's head = d>>3
    #pragma unroll
    for (int q = 0; q < 12; ++q) {
        #pragma unroll
        for (int ni = 0; ni < 2; ++ni) {
            const char* qp = smem + w * 6144 + ni * 3072 + q * 256 + (hslot ^ ((q & 7) << 5));
            uint4 pa = *(const uint4*)(qp);
            uint2 pbx = *(const uint2*)(qp + 16);
            const unsigned wds[6] = { pa.x, pa.y, pa.z, pa.w, pbx.x, pbx.y };
            float a = 0.f;
            #pragma unroll
            for (int p2 = 0; p2 < 6; ++p2) {
                a = fmaf(bitf(wds[p2] << 16),         vv[ni][2 * p2],     a);
                a = fmaf(bitf(wds[p2] & 0xFFFF0000u), vv[ni][2 * p2 + 1], a);
            }
            oacc[ni][q] = a;
        }
    }

    // ---- tbuf writes (v-slab; vv already in regs; r10 verbatim) ----
    #pragma unroll
    for (int ni = 0; ni < 2; ++ni)
        #pragma unroll
        for (int q = 0; q < 12; ++q)
            *(short*)(smem + vtOfs(w * 2 + ni, q, l)) = f2bf(oacc[ni][q]);
    lds_fence();

    const int l15c = (l15 < 12) ? l15 : 0;   // clamp B rows 12..15 (cols discarded)

    // ---- phase 3: FFN, wave-private, both ni (r10 verbatim) ----
    {
        bf16x8 w1f[4][2];
        float b1v[4];
        #pragma unroll
        for (int nt = 0; nt < 4; ++nt) {
            b1v[nt] = b1[nt * 16 + l15];
            #pragma unroll
            for (int kc = 0; kc < 2; ++kc)
                w1f[nt][kc] = *(const bf16x8*)(wt + 4096 + (nt * 16 + l15) * 64 + kc * 32 + l4 * 8);
        }
        #pragma unroll
        for (int ni = 0; ni < 2; ++ni) {
            const int slot = w * 2 + ni;
            bf16x8 a[2];
            #pragma unroll
            for (int kc = 0; kc < 2; ++kc)
                a[kc] = *(const bf16x8*)(smem + vtOfs(slot, l15c, kc * 32 + l4 * 8));
            #pragma unroll
            for (int nt = 0; nt < 4; ++nt) {
                f32x4 acc = { b1v[nt], b1v[nt], b1v[nt], b1v[nt] };
                acc = MFMA16(a[0], w1f[nt][0], acc);
                acc = MFMA16(a[1], w1f[nt][1], acc);
                #pragma unroll
                for (int reg = 0; reg < 4; ++reg) {
                    const int rt = l4 * 4 + reg;
                    if (rt < 12)
                        *(short*)(smem + vtOfs(slot, rt, nt * 16 + l15)) =
                            f2bf(fmaxf(acc[reg], 0.f));
                }
            }
        }
    }
    lds_fence();
    {
        bf16x8 w2f[4][2];
        float b2v[4];
        #pragma unroll
        for (int nt = 0; nt < 4; ++nt) {
            b2v[nt] = b2[nt * 16 + l15];
            #pragma unroll
            for (int kc = 0; kc < 2; ++kc)
                w2f[nt][kc] = *(const bf16x8*)(wt + 8192 + (nt * 16 + l15) * 64 + kc * 32 + l4 * 8);
        }
        #pragma unroll
        for (int ni = 0; ni < 2; ++ni) {
            const int slot = w * 2 + ni;
            bf16x8 a[2];
            #pragma unroll
            for (int kc = 0; kc < 2; ++kc)
                a[kc] = *(const bf16x8*)(smem + vtOfs(slot, l15c, kc * 32 + l4 * 8));
            #pragma unroll
            for (int nt = 0; nt < 4; ++nt) {
                f32x4 acc = { b2v[nt], b2v[nt], b2v[nt], b2v[nt] };
                acc = MFMA16(a[0], w2f[nt][0], acc);
                acc = MFMA16(a[1], w2f[nt][1], acc);
                #pragma unroll
                for (int reg = 0; reg < 4; ++reg) {
                    const int q = l4 * 4 + reg;
                    if (q < 12)
                        out[((size_t)(b * Ss + q) * Nn + n0 + slot) * Dd + nt * 16 + l15] = acc[reg];
                }
            }
        }
    }
}

extern "C" void kernel_launch(void* const* d_in, const int* in_sizes, int n_in,
                              void* d_out, int out_size, void* d_ws, size_t ws_size,
                              hipStream_t stream) {
    const float* x    = (const float*)d_in[0];
    const float* steP = (const float*)d_in[1];
    const float* steQ = (const float*)d_in[2];
    const float* Wff  = (const float*)d_in[3];
    const float* bff  = (const float*)d_in[4];
    const float* W1   = (const float*)d_in[5];
    const float* b1   = (const float*)d_in[6];
    const float* W2   = (const float*)d_in[7];
    const float* b2   = (const float*)d_in[8];
    float* out = (float*)d_out;
    unsigned short* wtp = (unsigned short*)d_ws;

    prep_w<<<48, 256, 0, stream>>>(Wff, W1, W2, wtp);
    dim3 grid(Nn / 8, Bb);
    ta_mfma14<<<grid, 256, 0, stream>>>(x, steP, steQ, bff, b1, b2, wtp, out);
}

// Round 17
// 122.893 us; speedup vs baseline: 1.2413x; 1.0411x over previous
//
#include <hip/hip_runtime.h>
#include <hip/hip_bf16.h>

// transformAttention fused MFMA kernel (round 17)
// r16 post-mortem: staged gload_lds = parity (serialization ate the gain), BUT
// VGPR_Count=68 under (256,3) proves the 64-VGPR "wall" was my (256,4) bound.
// r11's body (weight hoists + tbuf-in-v-slab + 3 fences) is verified-correct;
// its 135us was pure spill traffic (WRITE +16MB) under the 64-cap.
// Round 17 = r11 body + __launch_bounds__(256,3): budget 168 VGPR -> hoists
// stay in registers. Pressure audit ~100 peak; if allocator lands <=128, LDS
// (36864B) still gives 4 blocks/CU. One-line change from a verified kernel.
// LDS map (36864 B):
//   [0,12288)      q slab [12s][8n][64d] bf16, swz ((s&7)^(n&7))<<4
//   [12288,24576)  k slab (same) | after B2: per-(w,ni) pbuf (8x3072)
//   [24576,36864)  v slab (same) | after PV reads: per-(w,ni) tbuf (8x1536)

typedef __attribute__((ext_vector_type(8))) short bf16x8;
typedef __attribute__((ext_vector_type(4))) float f32x4;

constexpr int Bb = 16, Ss = 12, Nn = 2048, Dd = 64;
constexpr float EXPK = 0.51011687f;   // (1/sqrt(8)) * log2(e)
constexpr int KOFS = 12288, VOFS = 24576, LDSZ = 36864;

#define MFMA16(A, B, C) __builtin_amdgcn_mfma_f32_16x16x32_bf16((A), (B), (C), 0, 0, 0)

__device__ __forceinline__ short f2bf(float f) {
    __hip_bfloat16 h = __float2bfloat16(f);
    short s; __builtin_memcpy(&s, &h, 2); return s;
}
__device__ __forceinline__ float bitf(unsigned u) {
    float f; __builtin_memcpy(&f, &u, 4); return f;
}
__device__ __forceinline__ float bf2f(unsigned short v) {
    return bitf(((unsigned)v) << 16);
}
__device__ __forceinline__ unsigned cvtpk(float lo, float hi) {
    unsigned r;
    asm("v_cvt_pk_bf16_f32 %0, %1, %2" : "=v"(r) : "v"(lo), "v"(hi));
    return r;
}
__device__ __forceinline__ void lds_fence() {
    asm volatile("s_waitcnt lgkmcnt(0)" ::: "memory");
    __builtin_amdgcn_sched_barrier(0);
}
// q/k/v slab byte offset (single source of truth for the swizzle)
__device__ __forceinline__ int qkOfs(int t, int s, int n, int d) {
    return t * KOFS + s * 1024 + n * 128 + ((2 * d) ^ (((s & 7) ^ (n & 7)) << 4));
}
// tbuf in v-slab: slot = w*2+ni, 12 rows x 128 B
__device__ __forceinline__ int vtOfs(int slot, int row, int d) {
    return VOFS + slot * 1536 + row * 128 + ((2 * d) ^ ((row & 7) << 4));
}

// prep: d_ws <- bf16 W^T for Wff, W1, W2: wt[m][r*64+c] = W[c][r]
__global__ void prep_w(const float* __restrict__ Wff, const float* __restrict__ W1,
                       const float* __restrict__ W2, unsigned short* __restrict__ wt) {
    int idx = blockIdx.x * 256 + threadIdx.x;
    if (idx >= 3 * 4096) return;
    int m = idx >> 12, rc = idx & 4095, r = rc >> 6, c = rc & 63;
    const float* W = (m == 0) ? Wff : (m == 1) ? W1 : W2;
    unsigned short u; short s = f2bf(W[c * 64 + r]);
    __builtin_memcpy(&u, &s, 2);
    wt[idx] = u;
}

__global__ __launch_bounds__(256, 3)
void ta_mfma15(const float* __restrict__ x,
               const float* __restrict__ steP,
               const float* __restrict__ steQ,
               const float* __restrict__ bff, const float* __restrict__ b1,
               const float* __restrict__ b2,
               const unsigned short* __restrict__ wt,
               float* __restrict__ out)
{
    alignas(16) __shared__ char smem[LDSZ];

    const int tid = threadIdx.x;
    const int w   = tid >> 6;      // 0..3
    const int l   = tid & 63;
    const int l15 = l & 15;
    const int l4  = l >> 4;
    const int b   = blockIdx.y;
    const int n0  = blockIdx.x * 8;

    // ---- hoisted loads: W_ff frags, W1 frags, all biases ----
    bf16x8 wf[4][2], w1f[4][2];
    float bfv[4], b1v[4], b2v[4];
    #pragma unroll
    for (int nt = 0; nt < 4; ++nt) {
        bfv[nt] = bff[nt * 16 + l15];
        b1v[nt] = b1[nt * 16 + l15];
        b2v[nt] = b2[nt * 16 + l15];
        #pragma unroll
        for (int kc = 0; kc < 2; ++kc) {
            wf[nt][kc]  = *(const bf16x8*)(wt +        (nt * 16 + l15) * 64 + kc * 32 + l4 * 8);
            w1f[nt][kc] = *(const bf16x8*)(wt + 4096 + (nt * 16 + l15) * 64 + kc * 32 + l4 * 8);
        }
    }

    // ---- phase 1: projections, 18 jobs = 3 tensors x 6 s-pairs, 4 waves ----
    const int sA = l15 >> 3, nA = l15 & 7;
    for (int job = w; job < 18; job += 4) {
        const int t = job / 6, s0 = (job % 6) * 2;
        const float* base = (t == 0) ? steQ : (t == 1) ? steP : x;
        const float* rp = base + ((size_t)(b * Ss + s0 + sA) * Nn + n0 + nA) * Dd + l4 * 8;

        bf16x8 a[2];
        #pragma unroll
        for (int kc = 0; kc < 2; ++kc) {
            float4 p0 = *(const float4*)(rp + kc * 32);
            float4 p1 = *(const float4*)(rp + kc * 32 + 4);
            union { unsigned u[4]; bf16x8 v; } cv;
            cv.u[0] = cvtpk(p0.x, p0.y); cv.u[1] = cvtpk(p0.z, p0.w);
            cv.u[2] = cvtpk(p1.x, p1.y); cv.u[3] = cvtpk(p1.z, p1.w);
            a[kc] = cv.v;
        }
        #pragma unroll
        for (int nt = 0; nt < 4; ++nt) {
            f32x4 acc = { bfv[nt], bfv[nt], bfv[nt], bfv[nt] };
            acc = MFMA16(a[0], wf[nt][0], acc);
            acc = MFMA16(a[1], wf[nt][1], acc);
            const int d = nt * 16 + l15;
            #pragma unroll
            for (int q = 0; q < 4; ++q) {
                const int r = l4 * 4 + q, s = s0 + (r >> 3), nn = r & 7;
                *(short*)(smem + qkOfs(t, s, nn, d)) = f2bf(acc[q]);
            }
        }
    }
    __syncthreads();   // B1: q,k,v ready (hoisted vmem also drained here)

    // ---- v rows into regs (lane = d), both ni ----
    float vv[2][12];
    #pragma unroll
    for (int ni = 0; ni < 2; ++ni)
        #pragma unroll
        for (int s = 0; s < 12; ++s)
            vv[ni][s] = bf2f(*(const unsigned short*)(smem + qkOfs(2, s, w * 2 + ni, l)));

    // ---- phase 2a: per-head QK^T (swapped) + softmax; both ni interleaved ----
    unsigned pw[2][8][2];
    #pragma unroll
    for (int h = 0; h < 8; ++h) {
        #pragma unroll
        for (int ni = 0; ni < 2; ++ni) {
            const int n = w * 2 + ni;
            union { unsigned u[4]; bf16x8 v; } akk;
            akk.v = *(const bf16x8*)(smem + qkOfs(1, l15, n, h * 8));
            bf16x8 aq = *(const bf16x8*)(smem + qkOfs(0, l15, n, h * 8));
            if (l4 != 0) { akk.u[0] = 0; akk.u[1] = 0; akk.u[2] = 0; akk.u[3] = 0; }
            f32x4 c = { 0.f, 0.f, 0.f, 0.f };
            c = MFMA16(akk.v, aq, c);     // S^T: row p = l4*4+reg, col q = l15
            float e[4];
            #pragma unroll
            for (int i = 0; i < 4; ++i) {
                float v = __builtin_amdgcn_exp2f(c[i] * EXPK);
                e[i] = (l4 == 3) ? 0.f : v;     // zero p >= 12 / garbage rows
            }
            float ssum = (e[0] + e[1]) + (e[2] + e[3]);
            ssum += __shfl_xor(ssum, 16);
            ssum += __shfl_xor(ssum, 32);
            float inv;
            asm("v_rcp_f32 %0, %1" : "=v"(inv) : "v"(ssum));
            pw[ni][h][0] = cvtpk(e[0] * inv, e[1] * inv);
            pw[ni][h][1] = cvtpk(e[2] * inv, e[3] * inv);
        }
    }
    __syncthreads();   // B2: q,k slabs dead -> per-wave pbuf region

    // ---- phase 2b: pbuf scatter + VALU PV, both ni ----
    #pragma unroll
    for (int ni = 0; ni < 2; ++ni) {
        const int pb = w * 6144 + ni * 3072;
        if (l15 < 12 && l4 < 3) {
            #pragma unroll
            for (int h = 0; h < 8; ++h) {
                uint2 u; u.x = pw[ni][h][0]; u.y = pw[ni][h][1];
                *(uint2*)(smem + pb + l15 * 256 + ((h * 32) ^ ((l15 & 7) << 5)) + l4 * 8) = u;
            }
        }
    }
    lds_fence();   // F1: pbuf visible before PV reads

    float oacc[2][12];
    const int hslot = (l >> 3) * 32;   // lane's head = d>>3
    #pragma unroll
    for (int q = 0; q < 12; ++q) {
        #pragma unroll
        for (int ni = 0; ni < 2; ++ni) {
            const char* qp = smem + w * 6144 + ni * 3072 + q * 256 + (hslot ^ ((q & 7) << 5));
            uint4 pa = *(const uint4*)(qp);
            uint2 pbx = *(const uint2*)(qp + 16);
            const unsigned wds[6] = { pa.x, pa.y, pa.z, pa.w, pbx.x, pbx.y };
            float a = 0.f;
            #pragma unroll
            for (int p2 = 0; p2 < 6; ++p2) {
                a = fmaf(bitf(wds[p2] << 16),         vv[ni][2 * p2],     a);
                a = fmaf(bitf(wds[p2] & 0xFFFF0000u), vv[ni][2 * p2 + 1], a);
            }
            oacc[ni][q] = a;
        }
    }

    // ---- issue W2 frag loads here: hidden under tbuf writes + F2 + FFN1 ----
    bf16x8 w2f[4][2];
    #pragma unroll
    for (int nt = 0; nt < 4; ++nt)
        #pragma unroll
        for (int kc = 0; kc < 2; ++kc)
            w2f[nt][kc] = *(const bf16x8*)(wt + 8192 + (nt * 16 + l15) * 64 + kc * 32 + l4 * 8);

    // ---- tbuf writes (v-slab; vv already in regs; no fence vs PV reads) ----
    #pragma unroll
    for (int ni = 0; ni < 2; ++ni)
        #pragma unroll
        for (int q = 0; q < 12; ++q)
            *(short*)(smem + vtOfs(w * 2 + ni, q, l)) = f2bf(oacc[ni][q]);
    lds_fence();   // F2: tbuf visible before FFN1 reads

    const int l15c = (l15 < 12) ? l15 : 0;   // clamp B rows 12..15 (C cols discarded)

    // ---- phase 3: FFN, wave-private, both ni ----
    #pragma unroll
    for (int ni = 0; ni < 2; ++ni) {
        const int slot = w * 2 + ni;
        bf16x8 a[2];
        #pragma unroll
        for (int kc = 0; kc < 2; ++kc)
            a[kc] = *(const bf16x8*)(smem + vtOfs(slot, l15c, kc * 32 + l4 * 8));
        #pragma unroll
        for (int nt = 0; nt < 4; ++nt) {
            f32x4 acc = { b1v[nt], b1v[nt], b1v[nt], b1v[nt] };
            acc = MFMA16(a[0], w1f[nt][0], acc);
            acc = MFMA16(a[1], w1f[nt][1], acc);
            #pragma unroll
            for (int reg = 0; reg < 4; ++reg) {
                const int rt = l4 * 4 + reg;
                if (rt < 12)
                    *(short*)(smem + vtOfs(slot, rt, nt * 16 + l15)) =
                        f2bf(fmaxf(acc[reg], 0.f));
            }
        }
    }
    lds_fence();   // F3: hid visible before FFN2 reads
    #pragma unroll
    for (int ni = 0; ni < 2; ++ni) {
        const int slot = w * 2 + ni;
        bf16x8 a[2];
        #pragma unroll
        for (int kc = 0; kc < 2; ++kc)
            a[kc] = *(const bf16x8*)(smem + vtOfs(slot, l15c, kc * 32 + l4 * 8));
        #pragma unroll
        for (int nt = 0; nt < 4; ++nt) {
            f32x4 acc = { b2v[nt], b2v[nt], b2v[nt], b2v[nt] };
            acc = MFMA16(a[0], w2f[nt][0], acc);
            acc = MFMA16(a[1], w2f[nt][1], acc);
            #pragma unroll
            for (int reg = 0; reg < 4; ++reg) {
                const int q = l4 * 4 + reg;
                if (q < 12)
                    out[((size_t)(b * Ss + q) * Nn + n0 + slot) * Dd + nt * 16 + l15] = acc[reg];
            }
        }
    }
}

extern "C" void kernel_launch(void* const* d_in, const int* in_sizes, int n_in,
                              void* d_out, int out_size, void* d_ws, size_t ws_size,
                              hipStream_t stream) {
    const float* x    = (const float*)d_in[0];
    const float* steP = (const float*)d_in[1];
    const float* steQ = (const float*)d_in[2];
    const float* Wff  = (const float*)d_in[3];
    const float* bff  = (const float*)d_in[4];
    const float* W1   = (const float*)d_in[5];
    const float* b1   = (const float*)d_in[6];
    const float* W2   = (const float*)d_in[7];
    const float* b2   = (const float*)d_in[8];
    float* out = (float*)d_out;
    unsigned short* wtp = (unsigned short*)d_ws;

    prep_w<<<48, 256, 0, stream>>>(Wff, W1, W2, wtp);
    dim3 grid(Nn / 8, Bb);
    ta_mfma15<<<grid, 256, 0, stream>>>(x, steP, steQ, bff, b1, b2, wtp, out);
}